// Round 2
// baseline (6846.635 us; speedup 1.0000x reference)
//
#include <hip/hip_runtime.h>
#include <math.h>

#define B_    256
#define T_    512
#define COUT  320
#define NSUBJ 4
#define CI_CHUNK 16
#define TCO 64
#define TT 64

typedef unsigned int u32;

__device__ __forceinline__ float gelu_exact(float x) {
    return 0.5f * x * (1.0f + erff(x * 0.70710678118654752440f));
}

// ---------------------------------------------------------------------------
// Direct conv1d (K=3, SAME) with fused bias + optional residual. fp32 I/O.
// Block: 256 threads -> 64 co x 64 t tile for one batch.
// Thread: co_local = tid>>2, t-quarter q = tid&3 -> 16 consecutive t outputs.
// ---------------------------------------------------------------------------
__global__ __launch_bounds__(256) void conv_kernel(
    const float* __restrict__ in,    // [B, Cin, T]
    const float* __restrict__ w,     // [COUT, Cin, 3]
    const float* __restrict__ bias,  // [COUT]
    const float* __restrict__ res,   // [B, COUT, T] or nullptr
    float* __restrict__ out,         // [B, COUT, T]
    int Cin)
{
    __shared__ __align__(16) float Xs[CI_CHUNK][72];        // idx = t - t0 + 4, valid 3..68
    __shared__ __align__(16) float Ws[TCO][CI_CHUNK][4];    // [co][ci][tap], [3] zero

    const int tid = threadIdx.x;
    const int t0  = blockIdx.x * TT;
    const int co0 = blockIdx.y * TCO;
    const int b   = blockIdx.z;

    const int q   = tid & 3;
    const int col = tid >> 2;

    float acc[16];
    #pragma unroll
    for (int j = 0; j < 16; ++j) acc[j] = 0.f;

    const int inBase = b * Cin * T_;

    for (int ci0 = 0; ci0 < Cin; ci0 += CI_CHUNK) {
        // stage X: CI_CHUNK rows x 66 values (t0-1 .. t0+64), zero at edges/ci-overrun
        for (int i = tid; i < CI_CHUNK * 66; i += 256) {
            int r = i / 66;
            int p = i - r * 66;
            int ci = ci0 + r;
            int t = t0 - 1 + p;
            float v = 0.f;
            if (ci < Cin && t >= 0 && t < T_)
                v = in[inBase + ci * T_ + t];
            Xs[r][3 + p] = v;
        }
        // stage W: 64 co x CI_CHUNK ci x 3 taps (+ zero pad lane)
        for (int i = tid; i < TCO * CI_CHUNK; i += 256) {
            int r = i >> 4;
            int c = i & 15;
            int ci = ci0 + c;
            float w0 = 0.f, w1 = 0.f, w2 = 0.f;
            if (ci < Cin) {
                const float* wp = w + ((co0 + r) * Cin + ci) * 3;
                w0 = wp[0]; w1 = wp[1]; w2 = wp[2];
            }
            Ws[r][c][0] = w0; Ws[r][c][1] = w1; Ws[r][c][2] = w2; Ws[r][c][3] = 0.f;
        }
        __syncthreads();

        #pragma unroll
        for (int ci = 0; ci < CI_CHUNK; ++ci) {
            const float4 wv = *(const float4*)&Ws[col][ci][0];
            const float* xr = &Xs[ci][4 + q * 16];
            float x[18];
            x[0] = xr[-1];
            float4 m;
            m = *(const float4*)(xr +  0); x[1]=m.x;  x[2]=m.y;  x[3]=m.z;  x[4]=m.w;
            m = *(const float4*)(xr +  4); x[5]=m.x;  x[6]=m.y;  x[7]=m.z;  x[8]=m.w;
            m = *(const float4*)(xr +  8); x[9]=m.x;  x[10]=m.y; x[11]=m.z; x[12]=m.w;
            m = *(const float4*)(xr + 12); x[13]=m.x; x[14]=m.y; x[15]=m.z; x[16]=m.w;
            x[17] = xr[16];
            #pragma unroll
            for (int j = 0; j < 16; ++j) {
                acc[j] = fmaf(wv.x, x[j],     acc[j]);   // tap t-1
                acc[j] = fmaf(wv.y, x[j + 1], acc[j]);   // tap t
                acc[j] = fmaf(wv.z, x[j + 2], acc[j]);   // tap t+1
            }
        }
        __syncthreads();
    }

    const int co = co0 + col;
    const float bv = bias[co];
    const int outBase = (b * COUT + co) * T_ + t0 + q * 16;

    float v[16];
    #pragma unroll
    for (int j = 0; j < 16; ++j) v[j] = acc[j] + bv;

    if (res) {
        const float4* rp = (const float4*)(res + outBase);
        #pragma unroll
        for (int k = 0; k < 4; ++k) {
            float4 r = rp[k];
            v[4*k]     += r.x;
            v[4*k + 1] += r.y;
            v[4*k + 2] += r.z;
            v[4*k + 3] += r.w;
        }
    }

    float4* op = (float4*)(out + outBase);
    #pragma unroll
    for (int k = 0; k < 4; ++k)
        op[k] = make_float4(v[4*k], v[4*k+1], v[4*k+2], v[4*k+3]);
}

// ---------------------------------------------------------------------------
// Per-(subject, channel) partial sums/sumsq. Block = (co, batch-group of 32).
// Writes partials (no atomics -> no zero-init needed on poisoned ws).
// ---------------------------------------------------------------------------
__global__ __launch_bounds__(256) void stats_kernel(
    const float* __restrict__ x,   // [B, COUT, T]
    const int* __restrict__ subj,  // [B]
    float* __restrict__ part1,     // [8][NSUBJ][COUT]
    float* __restrict__ part2)
{
    const int co  = blockIdx.x;
    const int g   = blockIdx.y;
    const int tid = threadIdx.x;

    float s1[NSUBJ] = {0.f, 0.f, 0.f, 0.f};
    float s2[NSUBJ] = {0.f, 0.f, 0.f, 0.f};

    for (int bb = 0; bb < 32; ++bb) {
        int b = g * 32 + bb;
        int s = subj[b];                       // uniform across block
        float2 f = *(const float2*)(x + (b * COUT + co) * T_ + 2 * tid);
        float a1 = f.x + f.y;
        float a2 = f.x * f.x + f.y * f.y;
        if      (s == 0) { s1[0] += a1; s2[0] += a2; }
        else if (s == 1) { s1[1] += a1; s2[1] += a2; }
        else if (s == 2) { s1[2] += a1; s2[2] += a2; }
        else             { s1[3] += a1; s2[3] += a2; }
    }

    // wave reduce (width 64), then cross-wave via LDS
    #pragma unroll
    for (int s = 0; s < NSUBJ; ++s) {
        #pragma unroll
        for (int off = 32; off; off >>= 1) {
            s1[s] += __shfl_xor(s1[s], off, 64);
            s2[s] += __shfl_xor(s2[s], off, 64);
        }
    }
    __shared__ float red[2][NSUBJ][4];
    const int wave = tid >> 6;
    const int lane = tid & 63;
    if (lane == 0) {
        #pragma unroll
        for (int s = 0; s < NSUBJ; ++s) {
            red[0][s][wave] = s1[s];
            red[1][s][wave] = s2[s];
        }
    }
    __syncthreads();
    if (tid < 8) {
        int j = tid >> 2;
        int s = tid & 3;
        float t = red[j][s][0] + red[j][s][1] + red[j][s][2] + red[j][s][3];
        float* dst = j == 0 ? part1 : part2;
        dst[(g * NSUBJ + s) * COUT + co] = t;
    }
}

__global__ void finalize_kernel(
    const float* __restrict__ part1, const float* __restrict__ part2,
    const int* __restrict__ subj,
    const float* __restrict__ gamma, const float* __restrict__ beta,  // [NSUBJ][COUT]
    float* __restrict__ scale, float* __restrict__ shift)
{
    int idx = blockIdx.x * blockDim.x + threadIdx.x;
    if (idx >= NSUBJ * COUT) return;
    int s  = idx / COUT;
    float s1 = 0.f, s2 = 0.f;
    #pragma unroll
    for (int g = 0; g < 8; ++g) {
        s1 += part1[(g * NSUBJ) * COUT + idx % COUT + s * COUT];  // see note below
        s2 += part2[(g * NSUBJ) * COUT + idx % COUT + s * COUT];
    }
    // note: part layout is [g][s][co]; idx = s*COUT + co, so offset = (g*NSUBJ+s)*COUT+co
    //       = g*NSUBJ*COUT + idx. Rewrite cleanly:
    s1 = 0.f; s2 = 0.f;
    #pragma unroll
    for (int g = 0; g < 8; ++g) {
        s1 += part1[g * NSUBJ * COUT + idx];
        s2 += part2[g * NSUBJ * COUT + idx];
    }
    int nb = 0;
    for (int b = 0; b < B_; ++b) nb += (subj[b] == s) ? 1 : 0;
    float cnt  = fmaxf((float)nb * (float)T_, 1.0f);
    float mean = s1 / cnt;
    float var  = s2 / cnt - mean * mean;
    float sc = gamma[idx] * (1.0f / sqrtf(var + 1e-5f));
    float sh = beta[idx] - mean * sc;
    scale[idx] = sc;
    shift[idx] = sh;
}

__global__ __launch_bounds__(256) void bn_gelu_kernel(
    const float* __restrict__ x,
    const int* __restrict__ subj,
    const float* __restrict__ scale, const float* __restrict__ shift,
    float* __restrict__ out)
{
    int i4 = blockIdx.x * 256 + threadIdx.x;   // group of 4 elements
    int base = i4 * 4;
    int b   = base / (COUT * T_);
    int rem = base - b * (COUT * T_);
    int co  = rem >> 9;
    int s = subj[b];
    float sc = scale[s * COUT + co];
    float sh = shift[s * COUT + co];
    float4 v = *(const float4*)(x + base);
    float4 o;
    o.x = gelu_exact(v.x * sc + sh);
    o.y = gelu_exact(v.y * sc + sh);
    o.z = gelu_exact(v.z * sc + sh);
    o.w = gelu_exact(v.w * sc + sh);
    *(float4*)(out + base) = o;
}

// ---------------------------------------------------------------------------

extern "C" void kernel_launch(void* const* d_in, const int* in_sizes, int n_in,
                              void* d_out, int out_size, void* d_ws, size_t ws_size,
                              hipStream_t stream) {
    const float* X    = (const float*)d_in[0];
    const int*   subj = (const int*)d_in[1];
    const float* w0   = (const float*)d_in[2];
    const float* b0   = (const float*)d_in[3];
    const float* w1   = (const float*)d_in[4];
    const float* b1   = (const float*)d_in[5];
    const float* w2   = (const float*)d_in[6];
    const float* b2   = (const float*)d_in[7];
    const float* g0   = (const float*)d_in[8];
    const float* be0  = (const float*)d_in[9];
    const float* g1   = (const float*)d_in[10];
    const float* be1  = (const float*)d_in[11];
    const float* g2   = (const float*)d_in[12];
    const float* be2  = (const float*)d_in[13];
    float* outp = (float*)d_out;

    char* ws = (char*)d_ws;
    const size_t bufElems = (size_t)B_ * COUT * T_;        // 41,943,040
    float* buf0 = (float*)ws;                               // conv output (bn input)
    char* sb = ws + bufElems * sizeof(float);               // +167,772,160 B
    float* part1 = (float*)sb;                              // [8][4][COUT]
    float* part2 = part1 + 8 * NSUBJ * COUT;
    float* scale = part2 + 8 * NSUBJ * COUT;
    float* shift = scale + NSUBJ * COUT;
    // d_out doubles as the activation ping-pong buffer (fully rewritten each stage)

    const dim3 cgrid(T_ / TT, COUT / TCO, B_);              // (8, 5, 256)
    const dim3 sgrid(COUT, 8);
    const int agrid = (int)(bufElems / 4 / 256);            // 40960

    // ---- layer 0: conv(X, w0) + b0 -> buf0; bn+gelu -> d_out
    conv_kernel<<<cgrid, 256, 0, stream>>>(X, w0, b0, nullptr, buf0, 271);
    stats_kernel<<<sgrid, 256, 0, stream>>>(buf0, subj, part1, part2);
    finalize_kernel<<<5, 256, 0, stream>>>(part1, part2, subj, g0, be0, scale, shift);
    bn_gelu_kernel<<<agrid, 256, 0, stream>>>(buf0, subj, scale, shift, outp);

    // ---- layer 1: conv(x1, w1) + b1 + x1 -> buf0; bn+gelu -> d_out
    conv_kernel<<<cgrid, 256, 0, stream>>>(outp, w1, b1, outp, buf0, COUT);
    stats_kernel<<<sgrid, 256, 0, stream>>>(buf0, subj, part1, part2);
    finalize_kernel<<<5, 256, 0, stream>>>(part1, part2, subj, g1, be1, scale, shift);
    bn_gelu_kernel<<<agrid, 256, 0, stream>>>(buf0, subj, scale, shift, outp);

    // ---- layer 2: conv(x3, w2) + b2 + x3 -> buf0; bn+gelu -> d_out
    conv_kernel<<<cgrid, 256, 0, stream>>>(outp, w2, b2, outp, buf0, COUT);
    stats_kernel<<<sgrid, 256, 0, stream>>>(buf0, subj, part1, part2);
    finalize_kernel<<<5, 256, 0, stream>>>(part1, part2, subj, g2, be2, scale, shift);
    bn_gelu_kernel<<<agrid, 256, 0, stream>>>(buf0, subj, scale, shift, outp);
}

// Round 3
// 3549.269 us; speedup vs baseline: 1.9290x; 1.9290x over previous
//
#include <hip/hip_runtime.h>
#include <math.h>

#define B_    256
#define T_    512
#define COUT  320
#define NSUBJ 4

typedef unsigned int u32;
typedef unsigned short u16;

typedef __bf16 bf16x8 __attribute__((ext_vector_type(8)));
typedef float  f32x16 __attribute__((ext_vector_type(16)));

union FragU { uint2 u2[2]; bf16x8 v; };

__device__ __forceinline__ float bf2f(u16 u) {
    union { u32 i; float f; } v; v.i = ((u32)u) << 16; return v.f;
}
__device__ __forceinline__ u16 f2bf(float f) {
    union { float ff; u32 i; } v; v.ff = f;
    u32 x = v.i;
    x += 0x7fffu + ((x >> 16) & 1u);   // RNE
    return (u16)(x >> 16);
}
__device__ __forceinline__ float2 bfp2(u32 u) {
    float2 r;
    r.x = bf2f((u16)(u & 0xffffu));
    r.y = bf2f((u16)(u >> 16));
    return r;
}
__device__ __forceinline__ float gelu_exact(float x) {
    return 0.5f * x * (1.0f + erff(x * 0.70710678118654752440f));
}

// ---------------------------------------------------------------------------
// Implicit-GEMM conv1d (K=3 SAME) via mfma_f32_32x32x16_bf16.
// GEMM: M = t (512, whole row per block), N = co (64-tile), K = ci.
// Block: 4 waves; wave w covers t in [w*128, w*128+128) x all 64 co.
// IN_MODE 0: input fp32 [b][Cin][T] (layer 0, transpose while staging)
// IN_MODE 1: input bf16 [b][T][Cin] (act layout)
// OUT_BF16 : store bf16 [b][t][co] instead of fp32
// res      : bf16 [b][t][COUT] residual or nullptr
// ---------------------------------------------------------------------------
template<int IN_MODE, int OUT_BF16>
__global__ __launch_bounds__(256) void conv_mfma(
    const void* __restrict__ inp,
    const float* __restrict__ w,     // [COUT][Cin][3] fp32
    const float* __restrict__ bias,  // [COUT] fp32
    const u16* __restrict__ res,
    void* __restrict__ outp,
    int Cin)
{
    __shared__ u16 XsT[514][20];     // [t+1][ci], stride 20 (odd-bank) -> 2-way max
    __shared__ u16 Wt[3][64][20];    // [tap][co][ci]

    const int tid = threadIdx.x;
    const int b   = blockIdx.x;
    const int co0 = blockIdx.y * 64;

    const int lane = tid & 63;
    const int wv   = tid >> 6;
    const int l31  = lane & 31;
    const int kb   = (lane >> 5) * 8;   // k-half base (0 or 8)
    const int rofs = 4 * (lane >> 5);   // C/D row offset

    f32x16 acc[4][2];
    #pragma unroll
    for (int mi = 0; mi < 4; ++mi)
        #pragma unroll
        for (int ni = 0; ni < 2; ++ni)
            #pragma unroll
            for (int r = 0; r < 16; ++r) acc[mi][ni][r] = 0.f;

    const int nChunks = (Cin + 15) >> 4;
    for (int ch = 0; ch < nChunks; ++ch) {
        const int ci0 = ch << 4;
        // ---- stage input chunk -> XsT[t+1][ci]
        if (IN_MODE == 0) {
            const float* inF = (const float*)inp;
            for (int i = tid; i < 16 * 128; i += 256) {
                int ci = i >> 7, k = i & 127, t = k * 4;
                float4 v = make_float4(0.f, 0.f, 0.f, 0.f);
                if (ci0 + ci < Cin)
                    v = *(const float4*)(inF + ((size_t)b * Cin + ci0 + ci) * T_ + t);
                XsT[1 + t    ][ci] = f2bf(v.x);
                XsT[1 + t + 1][ci] = f2bf(v.y);
                XsT[1 + t + 2][ci] = f2bf(v.z);
                XsT[1 + t + 3][ci] = f2bf(v.w);
            }
            if (tid < 16) { XsT[0][tid] = 0; XsT[513][tid] = 0; }
        } else {
            const u16* inB = (const u16*)inp;
            for (int i = tid; i < 514 * 2; i += 256) {
                int row = i >> 1, part = i & 1;
                int t = row - 1;
                uint4 v = make_uint4(0u, 0u, 0u, 0u);
                if (t >= 0 && t < T_)
                    v = *(const uint4*)(inB + ((size_t)b * T_ + t) * Cin + ci0 + part * 8);
                *(uint2*)&XsT[row][part * 8]     = make_uint2(v.x, v.y);
                *(uint2*)&XsT[row][part * 8 + 4] = make_uint2(v.z, v.w);
            }
        }
        // ---- stage weight chunk -> Wt[tap][co][ci]
        for (int i = tid; i < 64 * 48; i += 256) {
            int co = i / 48, r = i - co * 48;
            int ci = r / 3, tap = r - ci * 3;
            float v = (ci0 + ci < Cin)
                    ? w[((size_t)(co0 + co) * Cin + ci0 + ci) * 3 + tap] : 0.f;
            Wt[tap][co][ci] = f2bf(v);
        }
        __syncthreads();

        // ---- 24 MFMA per wave per chunk
        #pragma unroll
        for (int tap = 0; tap < 3; ++tap) {
            FragU bw0, bw1;
            bw0.u2[0] = *(const uint2*)&Wt[tap][l31][kb];
            bw0.u2[1] = *(const uint2*)&Wt[tap][l31][kb + 4];
            bw1.u2[0] = *(const uint2*)&Wt[tap][32 + l31][kb];
            bw1.u2[1] = *(const uint2*)&Wt[tap][32 + l31][kb + 4];
            #pragma unroll
            for (int mi = 0; mi < 4; ++mi) {
                const int row = wv * 128 + mi * 32 + l31 + tap;  // t + tap - 1 + 1
                FragU ax;
                ax.u2[0] = *(const uint2*)&XsT[row][kb];
                ax.u2[1] = *(const uint2*)&XsT[row][kb + 4];
                acc[mi][0] = __builtin_amdgcn_mfma_f32_32x32x16_bf16(ax.v, bw0.v, acc[mi][0], 0, 0, 0);
                acc[mi][1] = __builtin_amdgcn_mfma_f32_32x32x16_bf16(ax.v, bw1.v, acc[mi][1], 0, 0, 0);
            }
        }
        __syncthreads();
    }

    // ---- epilogue: bias + residual + store
    #pragma unroll
    for (int ni = 0; ni < 2; ++ni) {
        const int co = co0 + ni * 32 + l31;
        const float bv = bias[co];
        #pragma unroll
        for (int mi = 0; mi < 4; ++mi) {
            #pragma unroll
            for (int r = 0; r < 16; ++r) {
                const int t = wv * 128 + mi * 32 + ((r & 3) + 8 * (r >> 2) + rofs);
                const size_t oi = ((size_t)b * T_ + t) * COUT + co;
                float v = acc[mi][ni][r] + bv;
                if (res) v += bf2f(res[oi]);
                if (OUT_BF16) ((u16*)outp)[oi] = f2bf(v);
                else          ((float*)outp)[oi] = v;
            }
        }
    }
}

// ---------------------------------------------------------------------------
// Per-(subject, channel) partial sums over [b][t][c] layout.
// grid (5 c-tiles, 64 b-groups of 4). Partials: [64][NSUBJ][COUT].
// ---------------------------------------------------------------------------
template<int BF>
__global__ __launch_bounds__(256) void stats_kernel(
    const void* __restrict__ xv, const int* __restrict__ subj,
    float* __restrict__ p1, float* __restrict__ p2)
{
    const int cl = threadIdx.x & 63;
    const int tq = threadIdx.x >> 6;
    const int c  = blockIdx.x * 64 + cl;
    const int g  = blockIdx.y;

    float s1[NSUBJ] = {0.f, 0.f, 0.f, 0.f};
    float s2[NSUBJ] = {0.f, 0.f, 0.f, 0.f};

    for (int bb = 0; bb < 4; ++bb) {
        const int b = g * 4 + bb;
        const int s = subj[b];          // uniform per block iteration
        float a1 = 0.f, a2 = 0.f;
        if (BF) {
            const u16* base = (const u16*)xv + (size_t)b * T_ * COUT + c;
            for (int t = tq; t < T_; t += 4) {
                float v = bf2f(base[(size_t)t * COUT]);
                a1 += v; a2 = fmaf(v, v, a2);
            }
        } else {
            const float* base = (const float*)xv + (size_t)b * T_ * COUT + c;
            for (int t = tq; t < T_; t += 4) {
                float v = base[(size_t)t * COUT];
                a1 += v; a2 = fmaf(v, v, a2);
            }
        }
        if      (s == 0) { s1[0] += a1; s2[0] += a2; }
        else if (s == 1) { s1[1] += a1; s2[1] += a2; }
        else if (s == 2) { s1[2] += a1; s2[2] += a2; }
        else             { s1[3] += a1; s2[3] += a2; }
    }

    __shared__ float r1[4][NSUBJ][64], r2[4][NSUBJ][64];
    #pragma unroll
    for (int s = 0; s < NSUBJ; ++s) { r1[tq][s][cl] = s1[s]; r2[tq][s][cl] = s2[s]; }
    __syncthreads();
    const int si = threadIdx.x >> 6;
    const float t1 = r1[0][si][cl] + r1[1][si][cl] + r1[2][si][cl] + r1[3][si][cl];
    const float t2 = r2[0][si][cl] + r2[1][si][cl] + r2[2][si][cl] + r2[3][si][cl];
    const size_t o = ((size_t)g * NSUBJ + si) * COUT + blockIdx.x * 64 + cl;
    p1[o] = t1; p2[o] = t2;
}

__global__ void finalize_kernel(
    const float* __restrict__ p1, const float* __restrict__ p2,
    const int* __restrict__ subj,
    const float* __restrict__ gamma, const float* __restrict__ beta,
    float* __restrict__ scale, float* __restrict__ shift)
{
    const int idx = blockIdx.x * blockDim.x + threadIdx.x;
    if (idx >= NSUBJ * COUT) return;
    const int s = idx / COUT;
    float s1 = 0.f, s2 = 0.f;
    for (int g = 0; g < 64; ++g) {
        s1 += p1[(size_t)g * NSUBJ * COUT + idx];
        s2 += p2[(size_t)g * NSUBJ * COUT + idx];
    }
    int nb = 0;
    for (int b = 0; b < B_; ++b) nb += (subj[b] == s) ? 1 : 0;
    const float cnt  = fmaxf((float)nb * (float)T_, 1.0f);
    const float mean = s1 / cnt;
    const float var  = s2 / cnt - mean * mean;
    const float sc = gamma[idx] * (1.0f / sqrtf(var + 1e-5f));
    scale[idx] = sc;
    shift[idx] = beta[idx] - mean * sc;
}

// elementwise BN+GELU on [b][t][c] fp32 -> bf16 act
__global__ __launch_bounds__(256) void bn_gelu_f2b(
    const float* __restrict__ x, const int* __restrict__ subj,
    const float* __restrict__ scale, const float* __restrict__ shift,
    u16* __restrict__ out)
{
    const size_t base = ((size_t)blockIdx.x * 256 + threadIdx.x) * 4;
    const int b = (int)(base / ((size_t)T_ * COUT));
    const int c = (int)(base % COUT);
    const int s = subj[b];
    const float4 v = *(const float4*)(x + base);
    const float4 sc = *(const float4*)(scale + (size_t)s * COUT + c);
    const float4 sh = *(const float4*)(shift + (size_t)s * COUT + c);
    const float y0 = gelu_exact(v.x * sc.x + sh.x);
    const float y1 = gelu_exact(v.y * sc.y + sh.y);
    const float y2 = gelu_exact(v.z * sc.z + sh.z);
    const float y3 = gelu_exact(v.w * sc.w + sh.w);
    *(uint2*)(out + base) = make_uint2((u32)f2bf(y0) | ((u32)f2bf(y1) << 16),
                                       (u32)f2bf(y2) | ((u32)f2bf(y3) << 16));
}

// final: BN+GELU + transpose [b][t][c] bf16 -> [b][c][t] fp32 (d_out)
__global__ __launch_bounds__(256) void final_tr(
    const u16* __restrict__ x, const int* __restrict__ subj,
    const float* __restrict__ scale, const float* __restrict__ shift,
    float* __restrict__ out)
{
    __shared__ float Lt[64][65];
    const int t0 = blockIdx.x * 64, c0 = blockIdx.y * 64, b = blockIdx.z;
    const int s = subj[b];
    {
        const int tt = threadIdx.x >> 2, chs = (threadIdx.x & 3) * 16;
        const u16* xp = x + ((size_t)b * T_ + t0 + tt) * COUT + c0 + chs;
        const uint4 u0 = *(const uint4*)xp;
        const uint4 u1 = *(const uint4*)(xp + 8);
        const u32 wd[8] = {u0.x, u0.y, u0.z, u0.w, u1.x, u1.y, u1.z, u1.w};
        const float* scp = scale + (size_t)s * COUT + c0 + chs;
        const float* shp = shift + (size_t)s * COUT + c0 + chs;
        #pragma unroll
        for (int k = 0; k < 8; ++k) {
            const float2 f = bfp2(wd[k]);
            Lt[tt][chs + 2 * k]     = gelu_exact(f.x * scp[2 * k]     + shp[2 * k]);
            Lt[tt][chs + 2 * k + 1] = gelu_exact(f.y * scp[2 * k + 1] + shp[2 * k + 1]);
        }
    }
    __syncthreads();
    {
        const int cr = threadIdx.x >> 2, tch = (threadIdx.x & 3) * 16;
        float* op = out + ((size_t)b * COUT + c0 + cr) * T_ + t0 + tch;
        #pragma unroll
        for (int k = 0; k < 16; k += 4)
            *(float4*)(op + k) = make_float4(Lt[tch + k][cr], Lt[tch + k + 1][cr],
                                             Lt[tch + k + 2][cr], Lt[tch + k + 3][cr]);
    }
}

// ---------------------------------------------------------------------------

extern "C" void kernel_launch(void* const* d_in, const int* in_sizes, int n_in,
                              void* d_out, int out_size, void* d_ws, size_t ws_size,
                              hipStream_t stream) {
    const float* X    = (const float*)d_in[0];
    const int*   subj = (const int*)d_in[1];
    const float* w0   = (const float*)d_in[2];
    const float* b0   = (const float*)d_in[3];
    const float* w1   = (const float*)d_in[4];
    const float* b1   = (const float*)d_in[5];
    const float* w2   = (const float*)d_in[6];
    const float* b2   = (const float*)d_in[7];
    const float* g0   = (const float*)d_in[8];
    const float* be0  = (const float*)d_in[9];
    const float* g1   = (const float*)d_in[10];
    const float* be1  = (const float*)d_in[11];
    const float* g2   = (const float*)d_in[12];
    const float* be2  = (const float*)d_in[13];

    const size_t actBytes = (size_t)B_ * T_ * COUT * 2;   // 83,886,080
    u16* act  = (u16*)d_ws;                                // bf16 activations [b][t][c]
    u16* bufB = (u16*)((char*)d_ws + actBytes);            // layer-2 conv out (bf16)

    // partials overlaid into dead regions:
    //  - layers 0/1: bufB region is unused until conv2 -> partials there
    //  - layer 2: act region is dead after conv2 reads it -> partials there
    float* p1a  = (float*)bufB;
    float* p2a  = p1a + 64 * NSUBJ * COUT;
    float* sc01 = p2a + 64 * NSUBJ * COUT;
    float* sh01 = sc01 + NSUBJ * COUT;
    float* p1b  = (float*)act;
    float* p2b  = p1b + 64 * NSUBJ * COUT;
    float* sc2  = p2b + 64 * NSUBJ * COUT;
    float* sh2  = sc2 + NSUBJ * COUT;

    float* convf = (float*)d_out;   // fp32 conv-out scratch for layers 0,1

    const dim3 cgrid(B_, COUT / 64);      // (256, 5): co-tiles of one b on one XCD
    const dim3 sgrid(COUT / 64, 64);      // (5, 64)
    const dim3 tgrid(T_ / 64, COUT / 64, B_);
    const int  agrid = (int)(((size_t)B_ * T_ * COUT) / 4 / 256);  // 40960

    // ---- layer 0
    conv_mfma<0, 0><<<cgrid, 256, 0, stream>>>(X, w0, b0, nullptr, convf, 271);
    stats_kernel<0><<<sgrid, 256, 0, stream>>>(convf, subj, p1a, p2a);
    finalize_kernel<<<5, 256, 0, stream>>>(p1a, p2a, subj, g0, be0, sc01, sh01);
    bn_gelu_f2b<<<agrid, 256, 0, stream>>>(convf, subj, sc01, sh01, act);

    // ---- layer 1
    conv_mfma<1, 0><<<cgrid, 256, 0, stream>>>(act, w1, b1, act, convf, COUT);
    stats_kernel<0><<<sgrid, 256, 0, stream>>>(convf, subj, p1a, p2a);
    finalize_kernel<<<5, 256, 0, stream>>>(p1a, p2a, subj, g1, be1, sc01, sh01);
    bn_gelu_f2b<<<agrid, 256, 0, stream>>>(convf, subj, sc01, sh01, act);

    // ---- layer 2
    conv_mfma<1, 1><<<cgrid, 256, 0, stream>>>(act, w2, b2, act, bufB, COUT);
    stats_kernel<1><<<sgrid, 256, 0, stream>>>(bufB, subj, p1b, p2b);
    finalize_kernel<<<5, 256, 0, stream>>>(p1b, p2b, subj, g2, be2, sc2, sh2);
    final_tr<<<tgrid, 256, 0, stream>>>(bufB, subj, sc2, sh2, (float*)d_out);
}

// Round 4
// 2125.654 us; speedup vs baseline: 3.2210x; 1.6697x over previous
//
#include <hip/hip_runtime.h>
#include <math.h>

#define B_    256
#define T_    512
#define TH    514          // T + 2 halo rows
#define CP    320          // padded channel stride (both Cin and Cout)
#define COUT  320
#define NSUBJ 4

typedef unsigned int u32;
typedef unsigned short u16;

typedef __bf16 bf16x8 __attribute__((ext_vector_type(8)));
typedef float  f32x16 __attribute__((ext_vector_type(16)));

union FragU { uint4 u4; bf16x8 v; };

__device__ __forceinline__ float bf2f(u16 u) {
    union { u32 i; float f; } v; v.i = ((u32)u) << 16; return v.f;
}
__device__ __forceinline__ u16 f2bf(float f) {
    union { float ff; u32 i; } v; v.ff = f;
    u32 x = v.i;
    x += 0x7fffu + ((x >> 16) & 1u);   // RNE
    return (u16)(x >> 16);
}
__device__ __forceinline__ float2 bfp2(u32 u) {
    float2 r;
    r.x = bf2f((u16)(u & 0xffffu));
    r.y = bf2f((u16)(u >> 16));
    return r;
}
__device__ __forceinline__ float gelu_exact(float x) {
    return 0.5f * x * (1.0f + erff(x * 0.70710678118654752440f));
}
__device__ __forceinline__ bf16x8 ldfrag(const u16* p) {
    FragU f; f.u4 = *(const uint4*)p; return f.v;
}

// ---------------------------------------------------------------------------
// prep_w: fp32 [co][Cin][3] -> bf16 [tap][co][CP] (ci >= Cin zeroed)
// ---------------------------------------------------------------------------
__global__ void prep_w(const float* __restrict__ w, u16* __restrict__ wb, int Cin) {
    const int idx = blockIdx.x * 256 + threadIdx.x;
    if (idx >= 3 * CP * CP) return;
    const int tap = idx / (CP * CP);
    const int r   = idx - tap * CP * CP;
    const int co  = r / CP;
    const int ci  = r - co * CP;
    const float v = (ci < Cin) ? w[((size_t)co * Cin + ci) * 3 + tap] : 0.f;
    wb[idx] = f2bf(v);
}

// zero halo rows (t=-1 and t=T) of the act buffer [B][TH][CP]
__global__ void zero_halo(u16* __restrict__ xh) {
    const int idx = blockIdx.x * 256 + threadIdx.x;   // 20480 uint4 total
    const int i8 = idx * 8;
    const int b = i8 / (2 * CP);
    const int r = i8 - b * 2 * CP;
    const int row = (r < CP) ? 0 : (TH - 1);
    const int c   = (r < CP) ? r : r - CP;
    *(uint4*)(xh + ((size_t)b * TH + row) * CP + c) = make_uint4(0u, 0u, 0u, 0u);
}

// prep_x: X fp32 [b][271][512] -> act bf16 [b][1+t][ci] (ci>=271 zero)
__global__ __launch_bounds__(256) void prep_x(
    const float* __restrict__ X, u16* __restrict__ xh) {
    __shared__ float Lt[64][65];
    const int t0 = blockIdx.x * 64, c0 = blockIdx.y * 64, b = blockIdx.z;
    {
        const int cr = threadIdx.x >> 2, tq = (threadIdx.x & 3) * 16;
        if (c0 + cr < 271) {
            const float* xp = X + ((size_t)b * 271 + c0 + cr) * 512 + t0 + tq;
            #pragma unroll
            for (int k = 0; k < 16; k += 4) {
                const float4 v = *(const float4*)(xp + k);
                Lt[cr][tq + k]     = v.x;
                Lt[cr][tq + k + 1] = v.y;
                Lt[cr][tq + k + 2] = v.z;
                Lt[cr][tq + k + 3] = v.w;
            }
        } else {
            #pragma unroll
            for (int k = 0; k < 16; ++k) Lt[cr][tq + k] = 0.f;
        }
    }
    __syncthreads();
    {
        const int tr = threadIdx.x >> 2, cq = (threadIdx.x & 3) * 16;
        u16 tmp[16];
        #pragma unroll
        for (int k = 0; k < 16; ++k) tmp[k] = f2bf(Lt[cq + k][tr]);
        u16* op = xh + ((size_t)b * TH + 1 + t0 + tr) * CP + c0 + cq;
        *(uint4*)op       = *(const uint4*)&tmp[0];
        *(uint4*)(op + 8) = *(const uint4*)&tmp[8];
    }
}

// ---------------------------------------------------------------------------
// Implicit-GEMM conv1d (K=3 SAME) via mfma_f32_32x32x16_bf16, pipelined.
// Input:  xh bf16 [B][TH][CP] (halo rows zero). Weights: wb bf16 [3][CP][CP].
// Block: 256 thr / 4 waves; tile M=256 t x N=64 co; wave: 64 t x 64 co.
// K-loop: 10 chunks of 32 ci, register-buffered prefetch pipeline.
// ---------------------------------------------------------------------------
template<int OUT_BF16, int HAS_RES>
__global__ __launch_bounds__(256, 3) void conv_mfma(
    const u16* __restrict__ xh,
    const u16* __restrict__ wb,
    const float* __restrict__ bias,
    const u16* __restrict__ res,     // halo layout [B][TH][CP] or unused
    void* __restrict__ outp)         // [B][T][CP] fp32 or bf16
{
    __shared__ u16 Xs[258][32];
    __shared__ u16 Ws[3][64][32];

    const int tid = threadIdx.x;
    const int t0  = blockIdx.x * 256;
    const int co0 = blockIdx.y * 64;
    const int b   = blockIdx.z;

    const int lane = tid & 63;
    const int wv   = tid >> 6;
    const int l31  = lane & 31;
    const int kb8  = (lane >> 5) * 8;
    const int rofs = (lane >> 5) * 4;

    f32x16 acc[2][2];
    #pragma unroll
    for (int mi = 0; mi < 2; ++mi)
        #pragma unroll
        for (int ni = 0; ni < 2; ++ni)
            #pragma unroll
            for (int r = 0; r < 16; ++r) acc[mi][ni][r] = 0.f;

    const u16* xbase = xh + ((size_t)b * TH + t0) * CP;   // local row 0 = Xh row t0
    const int xr = tid >> 2;
    const int xc = (tid & 3) * 8;

    uint4 xg[5];
    uint4 wg[3];

    auto loadChunk = [&](int ci0) {
        #pragma unroll
        for (int s = 0; s < 4; ++s)
            xg[s] = *(const uint4*)(xbase + (size_t)(s * 64 + xr) * CP + ci0 + xc);
        if (tid < 8)
            xg[4] = *(const uint4*)(xbase + (size_t)(256 + xr) * CP + ci0 + xc);
        #pragma unroll
        for (int s = 0; s < 3; ++s) {
            const int i = tid + s * 256;
            const int tap = i >> 8, co = (i & 255) >> 2, q = i & 3;
            wg[s] = *(const uint4*)(wb + ((size_t)tap * CP + co0 + co) * CP + ci0 + q * 8);
        }
    };
    auto storeChunk = [&]() {
        #pragma unroll
        for (int s = 0; s < 4; ++s)
            *(uint4*)&Xs[s * 64 + xr][xc] = xg[s];
        if (tid < 8)
            *(uint4*)&Xs[256 + xr][xc] = xg[4];
        #pragma unroll
        for (int s = 0; s < 3; ++s) {
            const int i = tid + s * 256;
            const int tap = i >> 8, co = (i & 255) >> 2, q = i & 3;
            *(uint4*)&Ws[tap][co][q * 8] = wg[s];
        }
    };

    loadChunk(0);
    for (int ch = 0; ch < 10; ++ch) {
        __syncthreads();
        storeChunk();
        __syncthreads();
        if (ch < 9) loadChunk((ch + 1) * 32);

        #pragma unroll
        for (int ks = 0; ks < 2; ++ks) {
            #pragma unroll
            for (int tap = 0; tap < 3; ++tap) {
                const bf16x8 bw0 = ldfrag(&Ws[tap][l31][ks * 16 + kb8]);
                const bf16x8 bw1 = ldfrag(&Ws[tap][32 + l31][ks * 16 + kb8]);
                #pragma unroll
                for (int mi = 0; mi < 2; ++mi) {
                    const bf16x8 av = ldfrag(&Xs[wv * 64 + mi * 32 + l31 + tap][ks * 16 + kb8]);
                    acc[mi][0] = __builtin_amdgcn_mfma_f32_32x32x16_bf16(av, bw0, acc[mi][0], 0, 0, 0);
                    acc[mi][1] = __builtin_amdgcn_mfma_f32_32x32x16_bf16(av, bw1, acc[mi][1], 0, 0, 0);
                }
            }
        }
    }

    // epilogue: bias + residual + store
    #pragma unroll
    for (int ni = 0; ni < 2; ++ni) {
        const int co = co0 + ni * 32 + l31;
        const float bv = bias[co];
        #pragma unroll
        for (int mi = 0; mi < 2; ++mi) {
            #pragma unroll
            for (int r = 0; r < 16; ++r) {
                const int t = t0 + wv * 64 + mi * 32 + (r & 3) + 8 * (r >> 2) + rofs;
                const size_t op = ((size_t)b * T_ + t) * CP + co;
                float v = acc[mi][ni][r] + bv;
                if (HAS_RES) v += bf2f(res[((size_t)b * TH + t + 1) * CP + co]);
                if (OUT_BF16) ((u16*)outp)[op] = f2bf(v);
                else          ((float*)outp)[op] = v;
            }
        }
    }
}

// ---------------------------------------------------------------------------
// Per-(subject, channel) partial sums over plain [b][t][c] layout.
// grid (5 c-tiles, 64 b-groups of 4). Partials: [64][NSUBJ][COUT].
// ---------------------------------------------------------------------------
template<int BF>
__global__ __launch_bounds__(256) void stats_kernel(
    const void* __restrict__ xv, const int* __restrict__ subj,
    float* __restrict__ p1, float* __restrict__ p2)
{
    const int cl = threadIdx.x & 63;
    const int tq = threadIdx.x >> 6;
    const int c  = blockIdx.x * 64 + cl;
    const int g  = blockIdx.y;

    float s1[NSUBJ] = {0.f, 0.f, 0.f, 0.f};
    float s2[NSUBJ] = {0.f, 0.f, 0.f, 0.f};

    for (int bb = 0; bb < 4; ++bb) {
        const int b = g * 4 + bb;
        const int s = subj[b];
        float a1 = 0.f, a2 = 0.f;
        if (BF) {
            const u16* base = (const u16*)xv + (size_t)b * T_ * COUT + c;
            for (int t = tq; t < T_; t += 4) {
                const float v = bf2f(base[(size_t)t * COUT]);
                a1 += v; a2 = fmaf(v, v, a2);
            }
        } else {
            const float* base = (const float*)xv + (size_t)b * T_ * COUT + c;
            for (int t = tq; t < T_; t += 4) {
                const float v = base[(size_t)t * COUT];
                a1 += v; a2 = fmaf(v, v, a2);
            }
        }
        if      (s == 0) { s1[0] += a1; s2[0] += a2; }
        else if (s == 1) { s1[1] += a1; s2[1] += a2; }
        else if (s == 2) { s1[2] += a1; s2[2] += a2; }
        else             { s1[3] += a1; s2[3] += a2; }
    }

    __shared__ float r1[4][NSUBJ][64], r2[4][NSUBJ][64];
    #pragma unroll
    for (int s = 0; s < NSUBJ; ++s) { r1[tq][s][cl] = s1[s]; r2[tq][s][cl] = s2[s]; }
    __syncthreads();
    const int si = threadIdx.x >> 6;
    const float t1 = r1[0][si][cl] + r1[1][si][cl] + r1[2][si][cl] + r1[3][si][cl];
    const float t2 = r2[0][si][cl] + r2[1][si][cl] + r2[2][si][cl] + r2[3][si][cl];
    const size_t o = ((size_t)g * NSUBJ + si) * COUT + blockIdx.x * 64 + cl;
    p1[o] = t1; p2[o] = t2;
}

__global__ void finalize_kernel(
    const float* __restrict__ p1, const float* __restrict__ p2,
    const int* __restrict__ subj,
    const float* __restrict__ gamma, const float* __restrict__ beta,
    float* __restrict__ scale, float* __restrict__ shift)
{
    const int idx = blockIdx.x * blockDim.x + threadIdx.x;
    if (idx >= NSUBJ * COUT) return;
    const int s = idx / COUT;
    float s1 = 0.f, s2 = 0.f;
    for (int g = 0; g < 64; ++g) {
        s1 += p1[(size_t)g * NSUBJ * COUT + idx];
        s2 += p2[(size_t)g * NSUBJ * COUT + idx];
    }
    int nb = 0;
    for (int b = 0; b < B_; ++b) nb += (subj[b] == s) ? 1 : 0;
    const float cnt  = fmaxf((float)nb * (float)T_, 1.0f);
    const float mean = s1 / cnt;
    const float var  = s2 / cnt - mean * mean;
    const float sc = gamma[idx] * (1.0f / sqrtf(var + 1e-5f));
    scale[idx] = sc;
    shift[idx] = beta[idx] - mean * sc;
}

// BN+GELU: convf fp32 plain [b][t][c] -> act bf16 halo layout [b][1+t][c]
__global__ __launch_bounds__(256) void bn_gelu_f2b(
    const float* __restrict__ x, const int* __restrict__ subj,
    const float* __restrict__ scale, const float* __restrict__ shift,
    u16* __restrict__ out)
{
    const size_t base = ((size_t)blockIdx.x * 256 + threadIdx.x) * 4;
    const int b = (int)(base / ((size_t)T_ * CP));
    const int r = (int)(base - (size_t)b * T_ * CP);
    const int t = r / CP;
    const int c = r - t * CP;
    const int s = subj[b];
    const float4 v  = *(const float4*)(x + base);
    const float4 sc = *(const float4*)(scale + (size_t)s * COUT + c);
    const float4 sh = *(const float4*)(shift + (size_t)s * COUT + c);
    const float y0 = gelu_exact(v.x * sc.x + sh.x);
    const float y1 = gelu_exact(v.y * sc.y + sh.y);
    const float y2 = gelu_exact(v.z * sc.z + sh.z);
    const float y3 = gelu_exact(v.w * sc.w + sh.w);
    u16* op = out + ((size_t)b * TH + 1 + t) * CP + c;
    *(uint2*)op = make_uint2((u32)f2bf(y0) | ((u32)f2bf(y1) << 16),
                             (u32)f2bf(y2) | ((u32)f2bf(y3) << 16));
}

// final: BN+GELU + transpose [b][t][c] bf16 plain -> [b][c][t] fp32 (d_out)
__global__ __launch_bounds__(256) void final_tr(
    const u16* __restrict__ x, const int* __restrict__ subj,
    const float* __restrict__ scale, const float* __restrict__ shift,
    float* __restrict__ out)
{
    __shared__ float Lt[64][65];
    const int t0 = blockIdx.x * 64, c0 = blockIdx.y * 64, b = blockIdx.z;
    const int s = subj[b];
    {
        const int tt = threadIdx.x >> 2, chs = (threadIdx.x & 3) * 16;
        const u16* xp = x + ((size_t)b * T_ + t0 + tt) * COUT + c0 + chs;
        const uint4 u0 = *(const uint4*)xp;
        const uint4 u1 = *(const uint4*)(xp + 8);
        const u32 wd[8] = {u0.x, u0.y, u0.z, u0.w, u1.x, u1.y, u1.z, u1.w};
        const float* scp = scale + (size_t)s * COUT + c0 + chs;
        const float* shp = shift + (size_t)s * COUT + c0 + chs;
        #pragma unroll
        for (int k = 0; k < 8; ++k) {
            const float2 f = bfp2(wd[k]);
            Lt[tt][chs + 2 * k]     = gelu_exact(f.x * scp[2 * k]     + shp[2 * k]);
            Lt[tt][chs + 2 * k + 1] = gelu_exact(f.y * scp[2 * k + 1] + shp[2 * k + 1]);
        }
    }
    __syncthreads();
    {
        const int cr = threadIdx.x >> 2, tch = (threadIdx.x & 3) * 16;
        float* op = out + ((size_t)b * COUT + c0 + cr) * T_ + t0 + tch;
        #pragma unroll
        for (int k = 0; k < 16; k += 4)
            *(float4*)(op + k) = make_float4(Lt[tch + k][cr], Lt[tch + k + 1][cr],
                                             Lt[tch + k + 2][cr], Lt[tch + k + 3][cr]);
    }
}

// ---------------------------------------------------------------------------

extern "C" void kernel_launch(void* const* d_in, const int* in_sizes, int n_in,
                              void* d_out, int out_size, void* d_ws, size_t ws_size,
                              hipStream_t stream) {
    const float* X    = (const float*)d_in[0];
    const int*   subj = (const int*)d_in[1];
    const float* w0   = (const float*)d_in[2];
    const float* b0   = (const float*)d_in[3];
    const float* w1   = (const float*)d_in[4];
    const float* b1   = (const float*)d_in[5];
    const float* w2   = (const float*)d_in[6];
    const float* b2   = (const float*)d_in[7];
    const float* g0   = (const float*)d_in[8];
    const float* be0  = (const float*)d_in[9];
    const float* g1   = (const float*)d_in[10];
    const float* be1  = (const float*)d_in[11];
    const float* g2   = (const float*)d_in[12];
    const float* be2  = (const float*)d_in[13];

    // ws layout
    const size_t actElems  = (size_t)B_ * TH * CP;      // 42,106,880  (84.21 MB)
    const size_t bufBElems = (size_t)B_ * T_ * CP;      // 41,943,040  (83.89 MB)
    u16* act  = (u16*)d_ws;
    u16* bufB = act + actElems;
    u16* wb0  = bufB + bufBElems;
    u16* wb1  = wb0 + 3 * CP * CP;
    u16* wb2  = wb1 + 3 * CP * CP;
    float* p1 = (float*)(wb2 + 3 * CP * CP);
    float* p2 = p1 + 64 * NSUBJ * COUT;
    float* sc = p2 + 64 * NSUBJ * COUT;
    float* sh = sc + NSUBJ * COUT;
    // total ~170.6 MB

    float* convf = (float*)d_out;   // fp32 conv-out scratch for layers 0,1

    const dim3 cgrid(2, 5, B_);            // conv: 2 t-tiles x 5 co-tiles x 256 b
    const dim3 sgrid(COUT / 64, 64);
    const dim3 pgrid(8, 5, B_);            // prep_x / final_tr tiles
    const int  agrid = (int)(((size_t)B_ * T_ * CP) / 4 / 256);   // 40960
    const int  wgrid = (3 * CP * CP + 255) / 256;                 // 1200

    // ---- preparation
    prep_w<<<wgrid, 256, 0, stream>>>(w0, wb0, 271);
    prep_w<<<wgrid, 256, 0, stream>>>(w1, wb1, 320);
    prep_w<<<wgrid, 256, 0, stream>>>(w2, wb2, 320);
    zero_halo<<<80, 256, 0, stream>>>(act);
    prep_x<<<pgrid, 256, 0, stream>>>(X, act);

    // ---- layer 0
    conv_mfma<0, 0><<<cgrid, 256, 0, stream>>>(act, wb0, b0, act, convf);
    stats_kernel<0><<<sgrid, 256, 0, stream>>>(convf, subj, p1, p2);
    finalize_kernel<<<5, 256, 0, stream>>>(p1, p2, subj, g0, be0, sc, sh);
    bn_gelu_f2b<<<agrid, 256, 0, stream>>>(convf, subj, sc, sh, act);

    // ---- layer 1 (residual)
    conv_mfma<0, 1><<<cgrid, 256, 0, stream>>>(act, wb1, b1, act, convf);
    stats_kernel<0><<<sgrid, 256, 0, stream>>>(convf, subj, p1, p2);
    finalize_kernel<<<5, 256, 0, stream>>>(p1, p2, subj, g1, be1, sc, sh);
    bn_gelu_f2b<<<agrid, 256, 0, stream>>>(convf, subj, sc, sh, act);

    // ---- layer 2 (residual, bf16 out)
    conv_mfma<1, 1><<<cgrid, 256, 0, stream>>>(act, wb2, b2, act, bufB);
    stats_kernel<1><<<sgrid, 256, 0, stream>>>(bufB, subj, p1, p2);
    finalize_kernel<<<5, 256, 0, stream>>>(p1, p2, subj, g2, be2, sc, sh);
    final_tr<<<pgrid, 256, 0, stream>>>(bufB, subj, sc, sh, (float*)d_out);
}